// Round 6
// baseline (3938.875 us; speedup 1.0000x reference)
//
#include <hip/hip_runtime.h>
#include <hip/hip_fp16.h>

// ---------------------------------------------------------------------------
// HeteroTripartiteGCN, round 6: bucketed-LDS-accumulation pipeline.
//   No CSR, no per-row sort. Destination rows are bucketed coarsely
//   (u/v: 256 rows/bucket, f: 64) -> 666 buckets total.
//   1) transforms (fp32 -> bf16 tables)
//   2) bucket histogram (666 bins, LDS-staged)
//   3) 666-entry exclusive scan (1 block)
//   4) bucketize: 8B records {col|src<<31, row_local<<16|fp16(val)} written
//      grouped by bucket (per-block chunks ~200B -> near-full-line writes)
//   5) accumulate: block per bucket, 64KB LDS fp32 accumulator, half-wave
//      per edge coalesced bf16 gather, ds_add_f32, fused ReLU store.
// d_out: [msg_u | msg_v | msg_f] fp32, every row written once (no memset).
// ---------------------------------------------------------------------------

#define TDIM 64
#define EPB  16384     // edges per block in hist/bucketize (64/thread)

struct Rel {
    const int* rows; const int* cols; const float* vals;
    int n, chunk0, boff, shift, srcflag;
};
struct RelPack { Rel r[6]; };

__device__ __forceinline__ unsigned short f2bf(float f) {
    union { float f; unsigned u; } c; c.f = f;
    unsigned r = c.u + 0x7FFFu + ((c.u >> 16) & 1u);  // RNE
    return (unsigned short)(r >> 16);
}
__device__ __forceinline__ float bflo(unsigned x) { return __uint_as_float(x << 16); }
__device__ __forceinline__ float bfhi(unsigned x) { return __uint_as_float(x & 0xFFFF0000u); }
__device__ __forceinline__ unsigned short h16(float f) {
    __half h = __float2half(f);
    return *reinterpret_cast<unsigned short*>(&h);
}
__device__ __forceinline__ float h16val(unsigned bits) {
    unsigned short s = (unsigned short)bits;
    __half h = *reinterpret_cast<__half*>(&s);
    return __half2float(h);
}

// ---------------- dense transforms (fp32 in, bf16 out) ----------------
__global__ __launch_bounds__(256) void transform2_kernel(
    const float* __restrict__ X, const float* __restrict__ W1,
    const float* __restrict__ W2, unsigned short* __restrict__ Y1,
    unsigned short* __restrict__ Y2, int N)
{
    __shared__ float xsT[64 * 68];
    __shared__ float w1s[64 * 64];
    __shared__ float w2s[64 * 64];

    const int tid  = threadIdx.x;
    const int row0 = blockIdx.x * 64;

    for (int i = tid * 4; i < 4096; i += 256 * 4) {
        *(float4*)&w1s[i] = *(const float4*)&W1[i];
        *(float4*)&w2s[i] = *(const float4*)&W2[i];
    }
    {
        const int r  = tid >> 2;
        const int c0 = (tid & 3) * 16;
        const int gr = row0 + r;
        #pragma unroll
        for (int cc = 0; cc < 16; cc += 4) {
            const int c = c0 + cc;
            float4 v = make_float4(0.f, 0.f, 0.f, 0.f);
            if (gr < N) v = *(const float4*)&X[(size_t)gr * TDIM + c];
            xsT[(c + 0) * 68 + r] = v.x;
            xsT[(c + 1) * 68 + r] = v.y;
            xsT[(c + 2) * 68 + r] = v.z;
            xsT[(c + 3) * 68 + r] = v.w;
        }
    }
    __syncthreads();

    const int tx = tid & 15;
    const int ty = tid >> 4;
    float a1[4][4] = {{0.f}}, a2[4][4] = {{0.f}};

    #pragma unroll 8
    for (int k = 0; k < 64; ++k) {
        const float4 xv = *(const float4*)&xsT[k * 68 + ty * 4];
        const float4 w1 = *(const float4*)&w1s[k * 64 + tx * 4];
        const float4 w2 = *(const float4*)&w2s[k * 64 + tx * 4];
        const float xr[4] = {xv.x, xv.y, xv.z, xv.w};
        const float c1[4] = {w1.x, w1.y, w1.z, w1.w};
        const float c2[4] = {w2.x, w2.y, w2.z, w2.w};
        #pragma unroll
        for (int r = 0; r < 4; ++r)
            #pragma unroll
            for (int c = 0; c < 4; ++c) {
                a1[r][c] = fmaf(xr[r], c1[c], a1[r][c]);
                a2[r][c] = fmaf(xr[r], c2[c], a2[r][c]);
            }
    }
    #pragma unroll
    for (int r = 0; r < 4; ++r) {
        const int gr = row0 + ty * 4 + r;
        if (gr < N) {
            ushort4 o1, o2;
            o1.x = f2bf(a1[r][0]); o1.y = f2bf(a1[r][1]);
            o1.z = f2bf(a1[r][2]); o1.w = f2bf(a1[r][3]);
            o2.x = f2bf(a2[r][0]); o2.y = f2bf(a2[r][1]);
            o2.z = f2bf(a2[r][2]); o2.w = f2bf(a2[r][3]);
            ((ushort4*)Y1)[(size_t)gr * 16 + tx] = o1;
            ((ushort4*)Y2)[(size_t)gr * 16 + tx] = o2;
        }
    }
}

__device__ __forceinline__ int find_rel(const RelPack& P, int chunk) {
    int ri = 0;
    if (chunk >= P.r[1].chunk0) ri = 1;
    if (chunk >= P.r[2].chunk0) ri = 2;
    if (chunk >= P.r[3].chunk0) ri = 3;
    if (chunk >= P.r[4].chunk0) ri = 4;
    if (chunk >= P.r[5].chunk0) ri = 5;
    return ri;
}

// ---------------- bucket histogram (666 bins) ----------------
__global__ __launch_bounds__(256) void bhist_kernel(
    RelPack P, int* __restrict__ bucketCnt, int NB)
{
    __shared__ int cnt[1024];
    const int tid = threadIdx.x;
    for (int t = tid; t < NB; t += 256) cnt[t] = 0;
    __syncthreads();

    const int ri = find_rel(P, blockIdx.x);
    const Rel M = P.r[ri];
    const int i0 = (blockIdx.x - M.chunk0) * EPB;
    for (int k = 0; k < EPB / 256; ++k) {
        const int i = i0 + tid + k * 256;
        if (i < M.n) {
            const int b = M.boff + (M.rows[i] >> M.shift);
            atomicAdd(&cnt[b], 1);
        }
    }
    __syncthreads();
    for (int t = tid; t < NB; t += 256)
        if (cnt[t]) atomicAdd(&bucketCnt[t], cnt[t]);
}

// ---------------- 666-entry exclusive scan, 1 block ----------------
__global__ __launch_bounds__(256) void bscan_kernel(
    const int* __restrict__ bucketCnt, int* __restrict__ bbase,
    int* __restrict__ gcur, int NB)
{
    __shared__ int sh[256];
    __shared__ int carry;
    const int t = threadIdx.x;
    if (t == 0) carry = 0;
    __syncthreads();
    for (int b0 = 0; b0 < NB; b0 += 256) {
        const int idx = b0 + t;
        const int c = (idx < NB) ? bucketCnt[idx] : 0;
        sh[t] = c;
        __syncthreads();
        for (int off = 1; off < 256; off <<= 1) {
            const int x = (t >= off) ? sh[t - off] : 0;
            __syncthreads();
            sh[t] += x;
            __syncthreads();
        }
        const int cbase = carry;
        const int excl  = cbase + sh[t] - c;
        if (idx < NB) { bbase[idx] = excl; gcur[idx] = excl; }
        __syncthreads();
        if (t == 0) carry = cbase + sh[255];
        __syncthreads();
    }
    if (t == 0) bbase[NB] = carry;
}

// ---------------- bucketize: grouped 8B record writes ----------------
__global__ __launch_bounds__(256) void bucketize_kernel(
    RelPack P, int* __restrict__ gcur, uint2* __restrict__ recs, int NB)
{
    __shared__ int cnt[1024];
    const int tid = threadIdx.x;
    for (int t = tid; t < NB; t += 256) cnt[t] = 0;
    __syncthreads();

    const int ri = find_rel(P, blockIdx.x);
    const Rel M = P.r[ri];
    const int i0 = (blockIdx.x - M.chunk0) * EPB;

    // pass 1: local bucket counts
    for (int k = 0; k < EPB / 256; ++k) {
        const int i = i0 + tid + k * 256;
        if (i < M.n) {
            const int b = M.boff + (M.rows[i] >> M.shift);
            atomicAdd(&cnt[b], 1);
        }
    }
    __syncthreads();

    // reserve global space per bucket; cnt[b] becomes this block's write base
    for (int t = tid; t < NB; t += 256) {
        const int c = cnt[t];
        cnt[t] = c ? atomicAdd(&gcur[t], c) : 0;
    }
    __syncthreads();

    // pass 2: write records
    const unsigned sflag = (unsigned)M.srcflag << 31;
    const int mask = (1 << M.shift) - 1;
    for (int k = 0; k < EPB / 256; ++k) {
        const int i = i0 + tid + k * 256;
        if (i < M.n) {
            const int row = M.rows[i];
            const int b   = M.boff + (row >> M.shift);
            const int pos = atomicAdd(&cnt[b], 1);
            uint2 rec;
            rec.x = (unsigned)M.cols[i] | sflag;
            rec.y = ((unsigned)(row & mask) << 16) | h16(M.vals[i]);
            recs[pos] = rec;
        }
    }
}

// ---------------- accumulate: block per bucket, LDS fp32 acc --------------
struct AccumPack {
    const unsigned* srcA[3]; const unsigned* srcB[3];
    int nbU, nbV;      // bucket counts for u, v
    int NU, NV, NF;
};

__global__ __launch_bounds__(256) void accum_kernel(
    AccumPack G, const int* __restrict__ bbase,
    const uint2* __restrict__ recs, float* __restrict__ out)
{
    extern __shared__ float acc[];
    const int b   = blockIdx.x;
    const int tid = threadIdx.x;

    int t, lb;
    if (b < G.nbU)               { t = 0; lb = b; }
    else if (b < G.nbU + G.nbV)  { t = 1; lb = b - G.nbU; }
    else                         { t = 2; lb = b - G.nbU - G.nbV; }
    const int shift     = (t == 2) ? 6 : 8;
    const int row_start = lb << shift;
    const int Ntype     = (t == 0) ? G.NU : (t == 1) ? G.NV : G.NF;
    const int nrows     = min(1 << shift, Ntype - row_start);
    const int obase     = (t == 0) ? 0 : (t == 1) ? G.NU : G.NU + G.NV;

    const int nz = nrows * TDIM;
    for (int i = tid; i < nz; i += 256) acc[i] = 0.f;
    __syncthreads();

    const unsigned* __restrict__ srcA = G.srcA[t];
    const unsigned* __restrict__ srcB = G.srcB[t];

    const int s = bbase[b];
    const int e = bbase[b + 1];
    const int hw  = tid >> 5;    // half-wave id 0..7
    const int sub = tid & 31;    // feature pair id

    for (int j = s + hw; j < e; j += 8) {
        const uint2 rec = recs[j];
        const unsigned w0 = rec.x, w1 = rec.y;
        const unsigned* __restrict__ src = (w0 & 0x80000000u) ? srcB : srcA;
        const unsigned col = w0 & 0x7FFFFFFFu;
        const unsigned x   = src[(size_t)col * 32 + sub];
        const float val = h16val(w1 & 0xFFFFu);
        const int   rl  = (int)(w1 >> 16);
        float* ar = &acc[rl * TDIM + sub * 2];
        atomicAdd(ar,     val * bflo(x));
        atomicAdd(ar + 1, val * bfhi(x));
    }
    __syncthreads();

    // epilogue: ReLU + coalesced store (every row written exactly once)
    const int n4 = nrows * 16;   // float4 count
    for (int i = tid; i < n4; i += 256) {
        const int r  = i >> 4;
        const int c4 = i & 15;
        float4 v = *(float4*)&acc[r * TDIM + c4 * 4];
        v.x = fmaxf(v.x, 0.f); v.y = fmaxf(v.y, 0.f);
        v.z = fmaxf(v.z, 0.f); v.w = fmaxf(v.w, 0.f);
        ((float4*)out)[(size_t)(obase + row_start + r) * 16 + c4] = v;
    }
}

// ---------------------------------------------------------------------------
extern "C" void kernel_launch(void* const* d_in, const int* in_sizes, int n_in,
                              void* d_out, int out_size, void* d_ws, size_t ws_size,
                              hipStream_t stream)
{
    const float* x_u    = (const float*)d_in[0];
    const float* x_v    = (const float*)d_in[1];
    const float* x_f    = (const float*)d_in[2];
    const float* W_u_uv = (const float*)d_in[3];
    const float* W_v_uv = (const float*)d_in[4];
    const float* W_f2u  = (const float*)d_in[5];
    const float* W_f2v  = (const float*)d_in[6];
    const float* W_u2f  = (const float*)d_in[7];
    const float* W_v2f  = (const float*)d_in[8];

    const int* rows_[6] = {(const int*)d_in[9],  (const int*)d_in[12],
                           (const int*)d_in[15], (const int*)d_in[18],
                           (const int*)d_in[21], (const int*)d_in[24]};
    const int* cols_[6] = {(const int*)d_in[10], (const int*)d_in[13],
                           (const int*)d_in[16], (const int*)d_in[19],
                           (const int*)d_in[22], (const int*)d_in[25]};
    const float* vals_[6] = {(const float*)d_in[11], (const float*)d_in[14],
                             (const float*)d_in[17], (const float*)d_in[20],
                             (const float*)d_in[23], (const float*)d_in[26]};

    const int NU = in_sizes[0] / TDIM;
    const int NV = in_sizes[1] / TDIM;
    const int NF = in_sizes[2] / TDIM;
    const int E_[6] = {in_sizes[9], in_sizes[12], in_sizes[15],
                       in_sizes[18], in_sizes[21], in_sizes[24]};

    const int nbU = (NU + 255) >> 8;
    const int nbV = (NV + 255) >> 8;
    const int nbF = (NF + 63) >> 6;
    const int NB  = nbU + nbV + nbF;           // 666 for the given sizes

    // rel -> (type, bucket offset, shift, src flag)
    // u: rel0 uv (srcA=tmp_v), rel2 uf (srcB=f2u)
    // v: rel1 vu (srcA=tmp_u), rel3 vf (srcB=f2v)
    // f: rel4 fu (srcA=u2f),  rel5 fv (srcB=v2f)
    const int boff_[6]  = {0, nbU, 0, nbU, nbU + nbV, nbU + nbV};
    const int shift_[6] = {8, 8, 8, 8, 6, 6};
    const int sflag_[6] = {0, 0, 1, 1, 0, 1};

    size_t etot = 0;
    for (int r = 0; r < 6; ++r) etot += (size_t)E_[r];

    // ---- workspace ----
    char* wsb = (char*)d_ws;
    size_t o = 0;
    auto alloc = [&](size_t bytes) {
        char* p = wsb + o;
        o = (o + bytes + 15) & ~(size_t)15;
        return p;
    };
    unsigned short* tmp_u = (unsigned short*)alloc((size_t)NU * TDIM * 2);
    unsigned short* u2f   = (unsigned short*)alloc((size_t)NU * TDIM * 2);
    unsigned short* tmp_v = (unsigned short*)alloc((size_t)NV * TDIM * 2);
    unsigned short* v2f   = (unsigned short*)alloc((size_t)NV * TDIM * 2);
    unsigned short* f2u   = (unsigned short*)alloc((size_t)NF * TDIM * 2);
    unsigned short* f2v   = (unsigned short*)alloc((size_t)NF * TDIM * 2);
    int* bucketCnt = (int*)alloc((size_t)NB * 4);
    int* bbase     = (int*)alloc((size_t)(NB + 1) * 4);
    int* gcur      = (int*)alloc((size_t)NB * 4);
    uint2* recs    = (uint2*)alloc(etot * 8);
    (void)ws_size;

    // ---- transforms ----
    transform2_kernel<<<(NU + 63) / 64, 256, 0, stream>>>(x_u, W_u_uv, W_u2f, tmp_u, u2f, NU);
    transform2_kernel<<<(NV + 63) / 64, 256, 0, stream>>>(x_v, W_v_uv, W_v2f, tmp_v, v2f, NV);
    transform2_kernel<<<(NF + 63) / 64, 256, 0, stream>>>(x_f, W_f2u, W_f2v, f2u, f2v, NF);

    // ---- relation pack / chunk map ----
    RelPack P;
    int chunks = 0;
    for (int r = 0; r < 6; ++r) {
        P.r[r].rows = rows_[r]; P.r[r].cols = cols_[r]; P.r[r].vals = vals_[r];
        P.r[r].n = E_[r]; P.r[r].chunk0 = chunks;
        P.r[r].boff = boff_[r]; P.r[r].shift = shift_[r]; P.r[r].srcflag = sflag_[r];
        chunks += (E_[r] + EPB - 1) / EPB;
    }

    // ---- bucket pipeline ----
    hipMemsetAsync(bucketCnt, 0, (size_t)NB * sizeof(int), stream);
    bhist_kernel<<<chunks, 256, 0, stream>>>(P, bucketCnt, NB);
    bscan_kernel<<<1, 256, 0, stream>>>(bucketCnt, bbase, gcur, NB);
    bucketize_kernel<<<chunks, 256, 0, stream>>>(P, gcur, recs, NB);

    // ---- accumulate ----
    AccumPack G;
    G.srcA[0] = (const unsigned*)tmp_v; G.srcB[0] = (const unsigned*)f2u;
    G.srcA[1] = (const unsigned*)tmp_u; G.srcB[1] = (const unsigned*)f2v;
    G.srcA[2] = (const unsigned*)u2f;   G.srcB[2] = (const unsigned*)v2f;
    G.nbU = nbU; G.nbV = nbV; G.NU = NU; G.NV = NV; G.NF = NF;

    accum_kernel<<<NB, 256, 65536, stream>>>(G, bbase, recs, (float*)d_out);
}

// Round 7
// 651.874 us; speedup vs baseline: 6.0424x; 6.0424x over previous
//
#include <hip/hip_runtime.h>
#include <hip/hip_fp16.h>

// ---------------------------------------------------------------------------
// HeteroTripartiteGCN, round 7: two-pass radix sort -> CSR -> gather.
//   1) transforms (fp32 -> bf16 tables)
//   2) coarse bucket (666 bins: u/v 256 rows, f 64 rows): LDS hist + grouped
//      8B record writes {col|flag<<31, row_local<<16|fp16(val)} (r6 kernels,
//      streams read ONCE)
//   3) fine sort: block per bucket, LDS (row_local,rel) count+scan, writes
//      global rowptr p2 and packed 4B arena {col<<15|fp16>>1}; scatter stays
//      inside the bucket's ~50KB L2-resident segment -> full-line writebacks
//   4) gather: wave per output row, half-wave per edge, bf16 pairs,
//      contiguous p2 walk, fused ReLU (r5's verified kernel shape)
// d_out: [msg_u | msg_v | msg_f] fp32, every row written exactly once.
// ---------------------------------------------------------------------------

#define TDIM 64
#define EPB  16384     // edges per block in hist/bucketize

struct Rel {
    const int* rows; const int* cols; const float* vals;
    int n, chunk0, boff, shift, srcflag;
};
struct RelPack { Rel r[6]; };

struct GatherPack {
    const unsigned* srcA[3]; const unsigned* srcB[3];
    int n0, n1;   // NU, NU+NV
};

__device__ __forceinline__ unsigned short f2bf(float f) {
    union { float f; unsigned u; } c; c.f = f;
    unsigned r = c.u + 0x7FFFu + ((c.u >> 16) & 1u);  // RNE
    return (unsigned short)(r >> 16);
}
__device__ __forceinline__ float bflo(unsigned x) { return __uint_as_float(x << 16); }
__device__ __forceinline__ float bfhi(unsigned x) { return __uint_as_float(x & 0xFFFF0000u); }
__device__ __forceinline__ unsigned short h16(float f) {
    __half h = __float2half(f);
    return *reinterpret_cast<unsigned short*>(&h);
}
__device__ __forceinline__ float h15val(unsigned packed) {
    unsigned short s = (unsigned short)((packed & 0x7FFFu) << 1);
    __half h = *reinterpret_cast<__half*>(&s);
    return __half2float(h);
}

// ---------------- dense transforms (fp32 in, bf16 out) ----------------
__global__ __launch_bounds__(256) void transform2_kernel(
    const float* __restrict__ X, const float* __restrict__ W1,
    const float* __restrict__ W2, unsigned short* __restrict__ Y1,
    unsigned short* __restrict__ Y2, int N)
{
    __shared__ float xsT[64 * 68];
    __shared__ float w1s[64 * 64];
    __shared__ float w2s[64 * 64];

    const int tid  = threadIdx.x;
    const int row0 = blockIdx.x * 64;

    for (int i = tid * 4; i < 4096; i += 256 * 4) {
        *(float4*)&w1s[i] = *(const float4*)&W1[i];
        *(float4*)&w2s[i] = *(const float4*)&W2[i];
    }
    {
        const int r  = tid >> 2;
        const int c0 = (tid & 3) * 16;
        const int gr = row0 + r;
        #pragma unroll
        for (int cc = 0; cc < 16; cc += 4) {
            const int c = c0 + cc;
            float4 v = make_float4(0.f, 0.f, 0.f, 0.f);
            if (gr < N) v = *(const float4*)&X[(size_t)gr * TDIM + c];
            xsT[(c + 0) * 68 + r] = v.x;
            xsT[(c + 1) * 68 + r] = v.y;
            xsT[(c + 2) * 68 + r] = v.z;
            xsT[(c + 3) * 68 + r] = v.w;
        }
    }
    __syncthreads();

    const int tx = tid & 15;
    const int ty = tid >> 4;
    float a1[4][4] = {{0.f}}, a2[4][4] = {{0.f}};

    #pragma unroll 8
    for (int k = 0; k < 64; ++k) {
        const float4 xv = *(const float4*)&xsT[k * 68 + ty * 4];
        const float4 w1 = *(const float4*)&w1s[k * 64 + tx * 4];
        const float4 w2 = *(const float4*)&w2s[k * 64 + tx * 4];
        const float xr[4] = {xv.x, xv.y, xv.z, xv.w};
        const float c1[4] = {w1.x, w1.y, w1.z, w1.w};
        const float c2[4] = {w2.x, w2.y, w2.z, w2.w};
        #pragma unroll
        for (int r = 0; r < 4; ++r)
            #pragma unroll
            for (int c = 0; c < 4; ++c) {
                a1[r][c] = fmaf(xr[r], c1[c], a1[r][c]);
                a2[r][c] = fmaf(xr[r], c2[c], a2[r][c]);
            }
    }
    #pragma unroll
    for (int r = 0; r < 4; ++r) {
        const int gr = row0 + ty * 4 + r;
        if (gr < N) {
            ushort4 o1, o2;
            o1.x = f2bf(a1[r][0]); o1.y = f2bf(a1[r][1]);
            o1.z = f2bf(a1[r][2]); o1.w = f2bf(a1[r][3]);
            o2.x = f2bf(a2[r][0]); o2.y = f2bf(a2[r][1]);
            o2.z = f2bf(a2[r][2]); o2.w = f2bf(a2[r][3]);
            ((ushort4*)Y1)[(size_t)gr * 16 + tx] = o1;
            ((ushort4*)Y2)[(size_t)gr * 16 + tx] = o2;
        }
    }
}

__device__ __forceinline__ int find_rel(const RelPack& P, int chunk) {
    int ri = 0;
    if (chunk >= P.r[1].chunk0) ri = 1;
    if (chunk >= P.r[2].chunk0) ri = 2;
    if (chunk >= P.r[3].chunk0) ri = 3;
    if (chunk >= P.r[4].chunk0) ri = 4;
    if (chunk >= P.r[5].chunk0) ri = 5;
    return ri;
}

// ---------------- coarse bucket histogram (666 bins) ----------------
__global__ __launch_bounds__(256) void bhist_kernel(
    RelPack P, int* __restrict__ bucketCnt, int NB)
{
    __shared__ int cnt[1024];
    const int tid = threadIdx.x;
    for (int t = tid; t < NB; t += 256) cnt[t] = 0;
    __syncthreads();

    const int ri = find_rel(P, blockIdx.x);
    const Rel M = P.r[ri];
    const int i0 = (blockIdx.x - M.chunk0) * EPB;
    for (int k = 0; k < EPB / 256; ++k) {
        const int i = i0 + tid + k * 256;
        if (i < M.n) {
            const int b = M.boff + (M.rows[i] >> M.shift);
            atomicAdd(&cnt[b], 1);
        }
    }
    __syncthreads();
    for (int t = tid; t < NB; t += 256)
        if (cnt[t]) atomicAdd(&bucketCnt[t], cnt[t]);
}

// ---------------- 666-entry exclusive scan, 1 block ----------------
__global__ __launch_bounds__(256) void bscan_kernel(
    const int* __restrict__ bucketCnt, int* __restrict__ bbase,
    int* __restrict__ gcur, int NB)
{
    __shared__ int sh[256];
    __shared__ int carry;
    const int t = threadIdx.x;
    if (t == 0) carry = 0;
    __syncthreads();
    for (int b0 = 0; b0 < NB; b0 += 256) {
        const int idx = b0 + t;
        const int c = (idx < NB) ? bucketCnt[idx] : 0;
        sh[t] = c;
        __syncthreads();
        for (int off = 1; off < 256; off <<= 1) {
            const int x = (t >= off) ? sh[t - off] : 0;
            __syncthreads();
            sh[t] += x;
            __syncthreads();
        }
        const int cbase = carry;
        const int excl  = cbase + sh[t] - c;
        if (idx < NB) { bbase[idx] = excl; gcur[idx] = excl; }
        __syncthreads();
        if (t == 0) carry = cbase + sh[255];
        __syncthreads();
    }
    if (t == 0) bbase[NB] = carry;
}

// ---------------- bucketize: grouped 8B record writes ----------------
__global__ __launch_bounds__(256) void bucketize_kernel(
    RelPack P, int* __restrict__ gcur, uint2* __restrict__ recs, int NB)
{
    __shared__ int cnt[1024];
    const int tid = threadIdx.x;
    for (int t = tid; t < NB; t += 256) cnt[t] = 0;
    __syncthreads();

    const int ri = find_rel(P, blockIdx.x);
    const Rel M = P.r[ri];
    const int i0 = (blockIdx.x - M.chunk0) * EPB;

    for (int k = 0; k < EPB / 256; ++k) {
        const int i = i0 + tid + k * 256;
        if (i < M.n) {
            const int b = M.boff + (M.rows[i] >> M.shift);
            atomicAdd(&cnt[b], 1);
        }
    }
    __syncthreads();

    for (int t = tid; t < NB; t += 256) {
        const int c = cnt[t];
        cnt[t] = c ? atomicAdd(&gcur[t], c) : 0;
    }
    __syncthreads();

    const unsigned sflag = (unsigned)M.srcflag << 31;
    const int mask = (1 << M.shift) - 1;
    for (int k = 0; k < EPB / 256; ++k) {
        const int i = i0 + tid + k * 256;
        if (i < M.n) {
            const int row = M.rows[i];
            const int b   = M.boff + (row >> M.shift);
            const int pos = atomicAdd(&cnt[b], 1);
            uint2 rec;
            rec.x = (unsigned)M.cols[i] | sflag;
            rec.y = ((unsigned)(row & mask) << 16) | h16(M.vals[i]);
            recs[pos] = rec;
        }
    }
}

// ---------------- fine sort: block per bucket -> rowptr p2 + 4B arena ------
__global__ __launch_bounds__(256) void finesort_kernel(
    const uint2* __restrict__ recs, const int* __restrict__ bbase,
    int* __restrict__ p2, unsigned* __restrict__ arena,
    int nbU, int nbV, int NU, int NV, int NF, int NB, int ntot_rows)
{
    __shared__ int cnt[512];
    __shared__ int excl[512];
    __shared__ int sh[256];

    const int b   = blockIdx.x;
    const int tid = threadIdx.x;

    int t, lb, rowbase;
    if (b < nbU)              { t = 0; lb = b;              rowbase = 0; }
    else if (b < nbU + nbV)   { t = 1; lb = b - nbU;        rowbase = NU; }
    else                      { t = 2; lb = b - nbU - nbV;  rowbase = NU + NV; }
    const int shift     = (t == 2) ? 6 : 8;
    const int Ntype     = (t == 0) ? NU : (t == 1) ? NV : NF;
    const int row_start = lb << shift;
    const int nrows     = min(1 << shift, Ntype - row_start);
    const int nbins     = (1 << shift) * 2;   // (row_local, rel)
    const int grow0     = rowbase + row_start;

    for (int i = tid; i < nbins; i += 256) cnt[i] = 0;
    __syncthreads();

    const int s = bbase[b];
    const int e = bbase[b + 1];

    // pass 1: count (row_local, rel)
    for (int j = s + tid; j < e; j += 256) {
        const uint2 r = recs[j];
        const int bin = (int)((r.y >> 16) << 1) | (int)(r.x >> 31);
        atomicAdd(&cnt[bin], 1);
    }
    __syncthreads();

    // exclusive scan over nbins (<=512) with 2 bins/thread
    const int i0 = 2 * tid, i1 = 2 * tid + 1;
    const int v0 = (i0 < nbins) ? cnt[i0] : 0;
    const int v1 = (i1 < nbins) ? cnt[i1] : 0;
    sh[tid] = v0 + v1;
    __syncthreads();
    for (int off = 1; off < 256; off <<= 1) {
        const int x = (tid >= off) ? sh[tid - off] : 0;
        __syncthreads();
        sh[tid] += x;
        __syncthreads();
    }
    const int base0 = (tid ? sh[tid - 1] : 0);
    if (i0 < nbins) { excl[i0] = base0; excl[i1] = base0 + v0; }
    __syncthreads();

    // rowptr: p2[2*grow + k] = arena start of (row,relk); monotone globally
    for (int i = tid; i < nrows * 2; i += 256)
        p2[2 * grow0 + i] = s + excl[i];
    if (b == NB - 1 && tid == 0) p2[2 * ntot_rows] = e;

    // cursors
    for (int i = tid; i < nbins; i += 256) cnt[i] = excl[i];
    __syncthreads();

    // pass 2: scatter packed 4B entries into bucket's arena segment (L2-hot)
    for (int j = s + tid; j < e; j += 256) {
        const uint2 r = recs[j];
        const int bin = (int)((r.y >> 16) << 1) | (int)(r.x >> 31);
        const int pos = s + atomicAdd(&cnt[bin], 1);
        const unsigned col = r.x & 0x7FFFFFFFu;
        arena[pos] = (col << 15) | ((r.y & 0xFFFFu) >> 1);
    }
}

// ---------------- gather: wave per row, half-wave per edge, ReLU -----------
__global__ __launch_bounds__(256) void gather_all_kernel(
    const int* __restrict__ p2, const unsigned* __restrict__ arena,
    GatherPack G, float* __restrict__ out, int nrow_total)
{
    const int wid  = (blockIdx.x * 256 + threadIdx.x) >> 6;
    const int lane = threadIdx.x & 63;
    const int half = lane >> 5;
    const int sub  = lane & 31;
    if (wid >= nrow_total) return;

    int seg = 0;
    if (wid >= G.n1)      seg = 2;
    else if (wid >= G.n0) seg = 1;

    const int pa = p2[2 * wid];
    const int pm = p2[2 * wid + 1];
    const int pe = p2[2 * wid + 2];

    float accx = 0.f, accy = 0.f;

    #pragma unroll
    for (int hh = 0; hh < 2; ++hh) {
        const unsigned* __restrict__ src = hh ? G.srcB[seg] : G.srcA[seg];
        const int s = hh ? pm : pa;
        const int e = hh ? pe : pm;
        int j = s;
        for (; j + 8 <= e; j += 8) {           // 8 edges: 4 per half-wave
            unsigned cv[4], x[4];
            #pragma unroll
            for (int q = 0; q < 4; ++q) cv[q] = arena[j + 2 * q + half];
            #pragma unroll
            for (int q = 0; q < 4; ++q)
                x[q] = src[(size_t)(cv[q] >> 15) * 32 + sub];
            #pragma unroll
            for (int q = 0; q < 4; ++q) {
                const float w = h15val(cv[q]);
                accx = fmaf(w, bflo(x[q]), accx);
                accy = fmaf(w, bfhi(x[q]), accy);
            }
        }
        for (; j + 2 <= e; j += 2) {
            const unsigned cv = arena[j + half];
            const unsigned x  = src[(size_t)(cv >> 15) * 32 + sub];
            const float w = h15val(cv);
            accx = fmaf(w, bflo(x), accx);
            accy = fmaf(w, bfhi(x), accy);
        }
        if (half == 0 && j < e) {
            const unsigned cv = arena[j];
            const unsigned x  = src[(size_t)(cv >> 15) * 32 + sub];
            const float w = h15val(cv);
            accx = fmaf(w, bflo(x), accx);
            accy = fmaf(w, bfhi(x), accy);
        }
    }

    accx += __shfl_xor(accx, 32, 64);
    accy += __shfl_xor(accy, 32, 64);
    if (half == 0) {
        float2 o = make_float2(fmaxf(accx, 0.f), fmaxf(accy, 0.f));
        ((float2*)out)[(size_t)wid * 32 + sub] = o;
    }
}

// ---------------------------------------------------------------------------
extern "C" void kernel_launch(void* const* d_in, const int* in_sizes, int n_in,
                              void* d_out, int out_size, void* d_ws, size_t ws_size,
                              hipStream_t stream)
{
    const float* x_u    = (const float*)d_in[0];
    const float* x_v    = (const float*)d_in[1];
    const float* x_f    = (const float*)d_in[2];
    const float* W_u_uv = (const float*)d_in[3];
    const float* W_v_uv = (const float*)d_in[4];
    const float* W_f2u  = (const float*)d_in[5];
    const float* W_f2v  = (const float*)d_in[6];
    const float* W_u2f  = (const float*)d_in[7];
    const float* W_v2f  = (const float*)d_in[8];

    const int* rows_[6] = {(const int*)d_in[9],  (const int*)d_in[12],
                           (const int*)d_in[15], (const int*)d_in[18],
                           (const int*)d_in[21], (const int*)d_in[24]};
    const int* cols_[6] = {(const int*)d_in[10], (const int*)d_in[13],
                           (const int*)d_in[16], (const int*)d_in[19],
                           (const int*)d_in[22], (const int*)d_in[25]};
    const float* vals_[6] = {(const float*)d_in[11], (const float*)d_in[14],
                             (const float*)d_in[17], (const float*)d_in[20],
                             (const float*)d_in[23], (const float*)d_in[26]};

    const int NU = in_sizes[0] / TDIM;
    const int NV = in_sizes[1] / TDIM;
    const int NF = in_sizes[2] / TDIM;
    const int E_[6] = {in_sizes[9], in_sizes[12], in_sizes[15],
                       in_sizes[18], in_sizes[21], in_sizes[24]};

    const int nbU = (NU + 255) >> 8;
    const int nbV = (NV + 255) >> 8;
    const int nbF = (NF + 63) >> 6;
    const int NB  = nbU + nbV + nbF;
    const int ntot_rows = NU + NV + NF;

    // u: rel0 uv (A=tmp_v), rel2 uf (B=f2u)
    // v: rel1 vu (A=tmp_u), rel3 vf (B=f2v)
    // f: rel4 fu (A=u2f),  rel5 fv (B=v2f)
    const int boff_[6]  = {0, nbU, 0, nbU, nbU + nbV, nbU + nbV};
    const int shift_[6] = {8, 8, 8, 8, 6, 6};
    const int sflag_[6] = {0, 0, 1, 1, 0, 1};

    size_t etot = 0;
    for (int r = 0; r < 6; ++r) etot += (size_t)E_[r];

    // ---- workspace ----
    char* wsb = (char*)d_ws;
    size_t o = 0;
    auto alloc = [&](size_t bytes) {
        char* p = wsb + o;
        o = (o + bytes + 15) & ~(size_t)15;
        return p;
    };
    unsigned short* tmp_u = (unsigned short*)alloc((size_t)NU * TDIM * 2);
    unsigned short* u2f   = (unsigned short*)alloc((size_t)NU * TDIM * 2);
    unsigned short* tmp_v = (unsigned short*)alloc((size_t)NV * TDIM * 2);
    unsigned short* v2f   = (unsigned short*)alloc((size_t)NV * TDIM * 2);
    unsigned short* f2u   = (unsigned short*)alloc((size_t)NF * TDIM * 2);
    unsigned short* f2v   = (unsigned short*)alloc((size_t)NF * TDIM * 2);
    int* bucketCnt = (int*)alloc((size_t)NB * 4);
    int* bbase     = (int*)alloc((size_t)(NB + 1) * 4);
    int* gcur      = (int*)alloc((size_t)NB * 4);
    int* p2        = (int*)alloc((size_t)(2 * ntot_rows + 1) * 4);
    uint2* recs    = (uint2*)alloc(etot * 8);
    unsigned* arena = (unsigned*)alloc(etot * 4);
    (void)ws_size;

    // ---- transforms ----
    transform2_kernel<<<(NU + 63) / 64, 256, 0, stream>>>(x_u, W_u_uv, W_u2f, tmp_u, u2f, NU);
    transform2_kernel<<<(NV + 63) / 64, 256, 0, stream>>>(x_v, W_v_uv, W_v2f, tmp_v, v2f, NV);
    transform2_kernel<<<(NF + 63) / 64, 256, 0, stream>>>(x_f, W_f2u, W_f2v, f2u, f2v, NF);

    // ---- relation pack ----
    RelPack P;
    int chunks = 0;
    for (int r = 0; r < 6; ++r) {
        P.r[r].rows = rows_[r]; P.r[r].cols = cols_[r]; P.r[r].vals = vals_[r];
        P.r[r].n = E_[r]; P.r[r].chunk0 = chunks;
        P.r[r].boff = boff_[r]; P.r[r].shift = shift_[r]; P.r[r].srcflag = sflag_[r];
        chunks += (E_[r] + EPB - 1) / EPB;
    }

    // ---- coarse bucket ----
    hipMemsetAsync(bucketCnt, 0, (size_t)NB * sizeof(int), stream);
    bhist_kernel<<<chunks, 256, 0, stream>>>(P, bucketCnt, NB);
    bscan_kernel<<<1, 256, 0, stream>>>(bucketCnt, bbase, gcur, NB);
    bucketize_kernel<<<chunks, 256, 0, stream>>>(P, gcur, recs, NB);

    // ---- fine sort to CSR ----
    finesort_kernel<<<NB, 256, 0, stream>>>(
        recs, bbase, p2, arena, nbU, nbV, NU, NV, NF, NB, ntot_rows);

    // ---- gather (+ReLU) ----
    GatherPack G;
    G.srcA[0] = (const unsigned*)tmp_v; G.srcB[0] = (const unsigned*)f2u;
    G.srcA[1] = (const unsigned*)tmp_u; G.srcB[1] = (const unsigned*)f2v;
    G.srcA[2] = (const unsigned*)u2f;   G.srcB[2] = (const unsigned*)v2f;
    G.n0 = NU; G.n1 = NU + NV;

    gather_all_kernel<<<(ntot_rows + 3) / 4, 256, 0, stream>>>(
        p2, arena, G, (float*)d_out, ntot_rows);
}